// Round 4
// baseline (340.332 us; speedup 1.0000x reference)
//
#include <hip/hip_runtime.h>
#include <hip/hip_bf16.h>
#include <math.h>

#define NS 2097152
#define NGROUP (NS / 16)        // 131072 groups of 16 samples
#define NBLOCK 2048
#define NWAVES (NBLOCK * 4)     // 8192 waves
#define ITERS (NGROUP / NWAVES) // 16, exact

typedef __attribute__((ext_vector_type(8))) short bf16x8;
typedef __attribute__((ext_vector_type(4))) float f32x4;

union FragU { unsigned u[4]; bf16x8 v; };

__device__ __forceinline__ unsigned pkbf16(float lo, float hi) {
    union { __hip_bfloat162 h; unsigned u; } cv;
    cv.h = __halves2bfloat162(__float2bfloat16(lo), __float2bfloat16(hi));
    return cv.u;
}

__global__ __launch_bounds__(256, 4) void radiance_mfma3_kernel(
    const float* __restrict__ features,
    const float* __restrict__ dirs,
    const float* __restrict__ normals,
    const float* __restrict__ W1,   // [35][64]
    const float* __restrict__ W2,   // [64][64]
    const float* __restrict__ W3,   // [64][3]
    float* __restrict__ out)        // [N][3]
{
    __shared__ __align__(16) unsigned char lds[4][4096];  // per-wave: h1 @0, h2 @2048

    const int tid  = threadIdx.x;
    const int wid  = tid >> 6;
    const int lane = tid & 63;
    const int s    = lane & 15;           // sample slot / column
    const int hi   = lane >> 4;           // 0..3
    const int wave_id = blockIdx.x * 4 + wid;

    unsigned char* wb  = &lds[wid][0];
    unsigned char* wb2 = wb + 2048;
    const unsigned sw = (unsigned)((s & 7) << 4);

    const f32x4 zero = {0.f, 0.f, 0.f, 0.f};

    // ---- hoisted, pre-swizzled LDS byte offsets ----
    unsigned wof[4], rof[2];
    #pragma unroll
    for (int t = 0; t < 4; ++t)
        wof[t] = ((unsigned)(s * 128 + t * 32 + hi * 8)) ^ sw;
    #pragma unroll
    for (int st = 0; st < 2; ++st)
        rof[st] = ((unsigned)(s * 128 + st * 64 + hi * 16)) ^ sw;

    // ================= one-time weight A-fragments =================
    // A = W^T: lane holds row m = t*16 + s, k = st*32 + hi*8 + j
    bf16x8 a1[4][2], a2[4][2], a3[2];

    #pragma unroll
    for (int t = 0; t < 4; ++t) {
        #pragma unroll
        for (int st = 0; st < 2; ++st) {
            FragU q;
            #pragma unroll
            for (int d = 0; d < 4; ++d) {
                int k0 = st * 32 + hi * 8 + 2 * d;
                int k1 = k0 + 1;
                int m  = t * 16 + s;
                float w0 = (k0 < 35) ? W1[k0 * 64 + m] : 0.f;
                float w1 = (k1 < 35) ? W1[k1 * 64 + m] : 0.f;
                q.u[d] = pkbf16(w0, w1);
            }
            a1[t][st] = q.v;
        }
    }
    #pragma unroll
    for (int t = 0; t < 4; ++t) {
        #pragma unroll
        for (int st = 0; st < 2; ++st) {
            FragU q;
            #pragma unroll
            for (int d = 0; d < 4; ++d) {
                int k0 = st * 32 + hi * 8 + 2 * d;
                int m  = t * 16 + s;
                q.u[d] = pkbf16(W2[k0 * 64 + m], W2[(k0 + 1) * 64 + m]);
            }
            a2[t][st] = q.v;
        }
    }
    #pragma unroll
    for (int st = 0; st < 2; ++st) {
        FragU q;
        #pragma unroll
        for (int d = 0; d < 4; ++d) {
            int k0 = st * 32 + hi * 8 + 2 * d;
            float w0 = (s < 3) ? W3[k0 * 3 + s] : 0.f;
            float w1 = (s < 3) ? W3[(k0 + 1) * 3 + s] : 0.f;
            q.u[d] = pkbf16(w0, w1);
        }
        a3[st] = q.v;
    }

    // ================= preload first group's inputs =================
    float4 cfA, cfB;
    float cdx, cdy, cdz, cnx, cny, cnz;
    {
        unsigned smp = (unsigned)wave_id * 16u + (unsigned)s;
        if (hi < 2) {
            const float* fb = features + (size_t)smp * 16 + hi * 8;
            cfA = *(const float4*)fb;
            cfB = *(const float4*)(fb + 4);
            if (hi == 0) {
                const float* np = normals + (size_t)smp * 3;
                cnx = np[0]; cny = np[1]; cnz = np[2];
            }
        } else {
            const float* dp = dirs + (size_t)smp * 3;
            const float* np = normals + (size_t)smp * 3;
            cdx = dp[0]; cdy = dp[1]; cdz = dp[2];
            cnx = np[0]; cny = np[1]; cnz = np[2];
        }
    }

    // ================= main loop: consume current, prefetch next =================
    unsigned g = (unsigned)wave_id;
    #pragma unroll 1
    for (int it = 0; it < ITERS; ++it) {
        const unsigned gn   = (it == ITERS - 1) ? g : g + (unsigned)NWAVES;
        const unsigned smpn = gn * 16u + (unsigned)s;

        // ---- build B fragments from current regs, then issue next loads ----
        unsigned u0, u1, u2, u3, v0, v1;
        if (hi < 2) {
            u0 = pkbf16(cfA.x, cfA.y); u1 = pkbf16(cfA.z, cfA.w);
            u2 = pkbf16(cfB.x, cfB.y); u3 = pkbf16(cfB.z, cfB.w);
            if (hi == 0) { v0 = pkbf16(cnx, cny); v1 = pkbf16(cnz, 0.f); }
            else         { v0 = 0; v1 = 0; }
            // prefetch next group's features (+ normals for hi==0)
            const float* fb = features + (size_t)smpn * 16 + hi * 8;
            cfA = *(const float4*)fb;
            cfB = *(const float4*)(fb + 4);
            if (hi == 0) {
                const float* np = normals + (size_t)smpn * 3;
                cnx = np[0]; cny = np[1]; cnz = np[2];
            }
        } else {
            float dn = cdx * cnx + cdy * cny + cdz * cnz;
            float m2 = -2.0f * dn;
            float x = fmaf(m2, cnx, cdx);
            float y = fmaf(m2, cny, cdy);
            float z = fmaf(m2, cnz, cdz);
            float xy = x * y, xz = x * z, yz = y * z;
            float x2 = x * x, y2 = y * y, z2 = z * z;
            float sh0 = 0.28209479177387814f;
            float sh1 = -0.48860251190291987f * y;
            float sh2 =  0.48860251190291987f * z;
            float sh3 = -0.48860251190291987f * x;
            float sh4 =  1.0925484305920792f * xy;
            float sh5 = -1.0925484305920792f * yz;
            float sh6 = fmaf(0.94617469575755997f, z2, -0.31539156525251999f);
            float sh7 = -1.0925484305920792f * xz;
            float sh8  = 0.54627421529603959f * (x2 - y2);
            float sh9  = 0.59004358992664352f * y * fmaf(-3.0f, x2, y2);
            float sh10 = 2.8906114426405538f * xy * z;
            float sh11 = 0.45704579946446572f * y * fmaf(-5.0f, z2, 1.0f);
            float sh12 = 0.3731763325901154f * z * fmaf(5.0f, z2, -3.0f);
            float sh13 = 0.45704579946446572f * x * fmaf(-5.0f, z2, 1.0f);
            float sh14 = 1.4453057213202769f * z * (x2 - y2);
            float sh15 = 0.59004358992664352f * x * fmaf(-1.0f, x2, 3.0f * y2);
            unsigned e0 = pkbf16(sh0, sh1),  e1 = pkbf16(sh2, sh3);
            unsigned e2 = pkbf16(sh4, sh5),  e3 = pkbf16(sh6, sh7);
            unsigned f0 = pkbf16(sh8, sh9),  f1 = pkbf16(sh10, sh11);
            unsigned f2 = pkbf16(sh12, sh13), f3 = pkbf16(sh14, sh15);
            bool odd = (hi & 1);
            u0 = odd ? f0 : e0; u1 = odd ? f1 : e1;
            u2 = odd ? f2 : e2; u3 = odd ? f3 : e3;
            v0 = 0; v1 = 0;
            // prefetch next group's dirs + normals
            const float* dp = dirs + (size_t)smpn * 3;
            const float* np = normals + (size_t)smpn * 3;
            cdx = dp[0]; cdy = dp[1]; cdz = dp[2];
            cnx = np[0]; cny = np[1]; cnz = np[2];
        }
        bf16x8 B0, B1v;
        { FragU q; q.u[0] = u0; q.u[1] = u1; q.u[2] = u2; q.u[3] = u3; B0 = q.v; }
        { FragU q; q.u[0] = v0; q.u[1] = v1; q.u[2] = 0;  q.u[3] = 0;  B1v = q.v; }

        // ---- layer 1 ----
        f32x4 acc1[4];
        #pragma unroll
        for (int t = 0; t < 4; ++t)
            acc1[t] = __builtin_amdgcn_mfma_f32_16x16x32_bf16(a1[t][0], B0, zero, 0, 0, 0);
        #pragma unroll
        for (int t = 0; t < 4; ++t)
            acc1[t] = __builtin_amdgcn_mfma_f32_16x16x32_bf16(a1[t][1], B1v, acc1[t], 0, 0, 0);

        // ---- relu + pack -> LDS (b64 writes) ----
        #pragma unroll
        for (int t = 0; t < 4; ++t) {
            uint2 w;
            w.x = pkbf16(fmaxf(acc1[t][0], 0.f), fmaxf(acc1[t][1], 0.f));
            w.y = pkbf16(fmaxf(acc1[t][2], 0.f), fmaxf(acc1[t][3], 0.f));
            *(uint2*)(wb + wof[t]) = w;
        }
        bf16x8 hB0 = *(const bf16x8*)(wb + rof[0]);
        bf16x8 hB1 = *(const bf16x8*)(wb + rof[1]);

        // ---- layer 2 ----
        f32x4 acc2[4];
        #pragma unroll
        for (int t = 0; t < 4; ++t)
            acc2[t] = __builtin_amdgcn_mfma_f32_16x16x32_bf16(a2[t][0], hB0, zero, 0, 0, 0);
        #pragma unroll
        for (int t = 0; t < 4; ++t)
            acc2[t] = __builtin_amdgcn_mfma_f32_16x16x32_bf16(a2[t][1], hB1, acc2[t], 0, 0, 0);

        // ---- relu + pack -> LDS buffer 2 ----
        #pragma unroll
        for (int t = 0; t < 4; ++t) {
            uint2 w;
            w.x = pkbf16(fmaxf(acc2[t][0], 0.f), fmaxf(acc2[t][1], 0.f));
            w.y = pkbf16(fmaxf(acc2[t][2], 0.f), fmaxf(acc2[t][3], 0.f));
            *(uint2*)(wb2 + wof[t]) = w;
        }
        bf16x8 hC0 = *(const bf16x8*)(wb2 + rof[0]);
        bf16x8 hC1 = *(const bf16x8*)(wb2 + rof[1]);

        // ---- layer 3 ----
        f32x4 acc3 = __builtin_amdgcn_mfma_f32_16x16x32_bf16(a3[0], hC0, zero, 0, 0, 0);
        acc3 = __builtin_amdgcn_mfma_f32_16x16x32_bf16(a3[1], hC1, acc3, 0, 0, 0);

        // ---- sigmoid + store ----
        float o0 = __fdividef(1.0f, 1.0f + __expf(-acc3[0]));
        float o1 = __fdividef(1.0f, 1.0f + __expf(-acc3[1]));
        float o2 = __fdividef(1.0f, 1.0f + __expf(-acc3[2]));
        if (hi == 0) {
            float* ob = out + (size_t)(g * 16u + (unsigned)s) * 3;
            ob[0] = o0; ob[1] = o1; ob[2] = o2;
        }
        g = gn;
    }
}

extern "C" void kernel_launch(void* const* d_in, const int* in_sizes, int n_in,
                              void* d_out, int out_size, void* d_ws, size_t ws_size,
                              hipStream_t stream) {
    const float* features = (const float*)d_in[0];
    const float* dirs     = (const float*)d_in[1];
    const float* normals  = (const float*)d_in[2];
    const float* W1       = (const float*)d_in[3];
    const float* W2       = (const float*)d_in[4];
    const float* W3       = (const float*)d_in[5];
    float* out = (float*)d_out;

    radiance_mfma3_kernel<<<NBLOCK, 256, 0, stream>>>(
        features, dirs, normals, W1, W2, W3, out);
}

// Round 9
// 290.255 us; speedup vs baseline: 1.1725x; 1.1725x over previous
//
#include <hip/hip_runtime.h>
#include <hip/hip_bf16.h>
#include <math.h>

#define NS 2097152
#define NGROUP (NS / 16)        // 131072 groups of 16 samples
#define NBLOCK 1024
#define NWAVES (NBLOCK * 4)     // 4096 waves
#define ITERS (NGROUP / NWAVES) // 32, exact

typedef __attribute__((ext_vector_type(8))) short bf16x8;
typedef __attribute__((ext_vector_type(4))) float f32x4;

union FragU { unsigned u[4]; bf16x8 v; };

__device__ __forceinline__ unsigned pkbf16(float lo, float hi) {
    union { __hip_bfloat162 h; unsigned u; } cv;
    cv.h = __halves2bfloat162(__float2bfloat16(lo), __float2bfloat16(hi));
    return cv.u;
}

// slot-permutation: slot p (0..63) -> neuron index
// p = st*32 + hi*8 + j ; neuron = (st*2 + (j>>2))*16 + hi*4 + (j&3)
__device__ __forceinline__ int permk(int p) {
    int st = p >> 5, hi = (p >> 3) & 3, j = p & 7;
    return (st * 2 + (j >> 2)) * 16 + hi * 4 + (j & 3);
}

__global__ __launch_bounds__(256, 4) void radiance_mfma4_kernel(
    const float* __restrict__ features,
    const float* __restrict__ dirs,
    const float* __restrict__ normals,
    const float* __restrict__ W1,   // [35][64]
    const float* __restrict__ W2,   // [64][64]
    const float* __restrict__ W3,   // [64][3]
    float* __restrict__ out)        // [N][3]
{
    const int tid  = threadIdx.x;
    const int wid  = tid >> 6;
    const int lane = tid & 63;
    const int s    = lane & 15;           // column: sample slot (B) / row (A)
    const int hi   = lane >> 4;           // 0..3
    const int wave_id = blockIdx.x * 4 + wid;

    const f32x4 zero = {0.f, 0.f, 0.f, 0.f};

    // ================= one-time weight A-fragments =================
    // layer 1: natural k (inputs are built in natural order)
    bf16x8 a1[4][2], a2[4][2], a3[2];
    #pragma unroll
    for (int t = 0; t < 4; ++t) {
        #pragma unroll
        for (int st = 0; st < 2; ++st) {
            FragU q;
            #pragma unroll
            for (int d = 0; d < 4; ++d) {
                int k0 = st * 32 + hi * 8 + 2 * d;
                int k1 = k0 + 1;
                int m  = t * 16 + s;
                float w0 = (k0 < 35) ? W1[k0 * 64 + m] : 0.f;
                float w1 = (k1 < 35) ? W1[k1 * 64 + m] : 0.f;
                q.u[d] = pkbf16(w0, w1);
            }
            a1[t][st] = q.v;
        }
    }
    // layer 2: k-slots permuted by permk (B2 is lane-local acc1 data)
    #pragma unroll
    for (int t = 0; t < 4; ++t) {
        #pragma unroll
        for (int st = 0; st < 2; ++st) {
            FragU q;
            #pragma unroll
            for (int d = 0; d < 4; ++d) {
                int p0 = st * 32 + hi * 8 + 2 * d;
                int n0 = permk(p0), n1 = permk(p0 + 1);
                int m  = t * 16 + s;
                q.u[d] = pkbf16(W2[n0 * 64 + m], W2[n1 * 64 + m]);
            }
            a2[t][st] = q.v;
        }
    }
    // layer 3: k-slots permuted; output channel c placed at row m = 4*c
    {
        bool live = ((s & 3) == 0) && (s < 12);
        int ch = s >> 2;
        #pragma unroll
        for (int st = 0; st < 2; ++st) {
            FragU q;
            #pragma unroll
            for (int d = 0; d < 4; ++d) {
                int p0 = st * 32 + hi * 8 + 2 * d;
                int n0 = permk(p0), n1 = permk(p0 + 1);
                float w0 = live ? W3[n0 * 3 + ch] : 0.f;
                float w1 = live ? W3[n1 * 3 + ch] : 0.f;
                q.u[d] = pkbf16(w0, w1);
            }
            a3[st] = q.v;
        }
    }

    // ================= preload first group's inputs =================
    float4 cfA, cfB;
    float cdx, cdy, cdz, cnx, cny, cnz;
    {
        unsigned smp = (unsigned)wave_id * 16u + (unsigned)s;
        if (hi < 2) {
            const float* fb = features + (size_t)smp * 16 + hi * 8;
            cfA = *(const float4*)fb;
            cfB = *(const float4*)(fb + 4);
            if (hi == 0) {
                const float* np = normals + (size_t)smp * 3;
                cnx = np[0]; cny = np[1]; cnz = np[2];
            }
        } else {
            const float* dp = dirs + (size_t)smp * 3;
            const float* np = normals + (size_t)smp * 3;
            cdx = dp[0]; cdy = dp[1]; cdz = dp[2];
            cnx = np[0]; cny = np[1]; cnz = np[2];
        }
    }

    // ================= main loop =================
    unsigned g = (unsigned)wave_id;
    #pragma unroll 1
    for (int it = 0; it < ITERS; ++it) {
        const unsigned gn   = (it == ITERS - 1) ? g : g + (unsigned)NWAVES;
        const unsigned smpn = gn * 16u + (unsigned)s;

        // ---- build B1 from current regs, then issue next loads ----
        unsigned u0, u1, u2, u3, v0, v1;
        if (hi < 2) {
            u0 = pkbf16(cfA.x, cfA.y); u1 = pkbf16(cfA.z, cfA.w);
            u2 = pkbf16(cfB.x, cfB.y); u3 = pkbf16(cfB.z, cfB.w);
            if (hi == 0) { v0 = pkbf16(cnx, cny); v1 = pkbf16(cnz, 0.f); }
            else         { v0 = 0; v1 = 0; }
            const float* fb = features + (size_t)smpn * 16 + hi * 8;
            cfA = *(const float4*)fb;
            cfB = *(const float4*)(fb + 4);
            if (hi == 0) {
                const float* np = normals + (size_t)smpn * 3;
                cnx = np[0]; cny = np[1]; cnz = np[2];
            }
        } else {
            float dn = cdx * cnx + cdy * cny + cdz * cnz;
            float m2 = -2.0f * dn;
            float x = fmaf(m2, cnx, cdx);
            float y = fmaf(m2, cny, cdy);
            float z = fmaf(m2, cnz, cdz);
            float xy = x * y, xz = x * z, yz = y * z;
            float x2 = x * x, y2 = y * y, z2 = z * z;
            float sh0 = 0.28209479177387814f;
            float sh1 = -0.48860251190291987f * y;
            float sh2 =  0.48860251190291987f * z;
            float sh3 = -0.48860251190291987f * x;
            float sh4 =  1.0925484305920792f * xy;
            float sh5 = -1.0925484305920792f * yz;
            float sh6 = fmaf(0.94617469575755997f, z2, -0.31539156525251999f);
            float sh7 = -1.0925484305920792f * xz;
            float sh8  = 0.54627421529603959f * (x2 - y2);
            float sh9  = 0.59004358992664352f * y * fmaf(-3.0f, x2, y2);
            float sh10 = 2.8906114426405538f * xy * z;
            float sh11 = 0.45704579946446572f * y * fmaf(-5.0f, z2, 1.0f);
            float sh12 = 0.3731763325901154f * z * fmaf(5.0f, z2, -3.0f);
            float sh13 = 0.45704579946446572f * x * fmaf(-5.0f, z2, 1.0f);
            float sh14 = 1.4453057213202769f * z * (x2 - y2);
            float sh15 = 0.59004358992664352f * x * fmaf(-1.0f, x2, 3.0f * y2);
            unsigned e0 = pkbf16(sh0, sh1),  e1 = pkbf16(sh2, sh3);
            unsigned e2 = pkbf16(sh4, sh5),  e3 = pkbf16(sh6, sh7);
            unsigned f0 = pkbf16(sh8, sh9),  f1 = pkbf16(sh10, sh11);
            unsigned f2 = pkbf16(sh12, sh13), f3 = pkbf16(sh14, sh15);
            bool odd = (hi & 1);
            u0 = odd ? f0 : e0; u1 = odd ? f1 : e1;
            u2 = odd ? f2 : e2; u3 = odd ? f3 : e3;
            v0 = 0; v1 = 0;
            const float* dp = dirs + (size_t)smpn * 3;
            const float* np = normals + (size_t)smpn * 3;
            cdx = dp[0]; cdy = dp[1]; cdz = dp[2];
            cnx = np[0]; cny = np[1]; cnz = np[2];
        }
        bf16x8 B0, B1v;
        { FragU q; q.u[0] = u0; q.u[1] = u1; q.u[2] = u2; q.u[3] = u3; B0 = q.v; }
        { FragU q; q.u[0] = v0; q.u[1] = v1; q.u[2] = 0;  q.u[3] = 0;  B1v = q.v; }

        // ---- layer 1 ----
        f32x4 acc1[4];
        #pragma unroll
        for (int t = 0; t < 4; ++t)
            acc1[t] = __builtin_amdgcn_mfma_f32_16x16x32_bf16(a1[t][0], B0, zero, 0, 0, 0);
        #pragma unroll
        for (int t = 0; t < 4; ++t)
            acc1[t] = __builtin_amdgcn_mfma_f32_16x16x32_bf16(a1[t][1], B1v, acc1[t], 0, 0, 0);

        // ---- relu + repack (lane-local, permuted k) -> B2 ----
        bf16x8 B2[2];
        #pragma unroll
        for (int st = 0; st < 2; ++st) {
            FragU q;
            q.u[0] = pkbf16(fmaxf(acc1[st*2][0],   0.f), fmaxf(acc1[st*2][1],   0.f));
            q.u[1] = pkbf16(fmaxf(acc1[st*2][2],   0.f), fmaxf(acc1[st*2][3],   0.f));
            q.u[2] = pkbf16(fmaxf(acc1[st*2+1][0], 0.f), fmaxf(acc1[st*2+1][1], 0.f));
            q.u[3] = pkbf16(fmaxf(acc1[st*2+1][2], 0.f), fmaxf(acc1[st*2+1][3], 0.f));
            B2[st] = q.v;
        }

        // ---- layer 2 ----
        f32x4 acc2[4];
        #pragma unroll
        for (int t = 0; t < 4; ++t)
            acc2[t] = __builtin_amdgcn_mfma_f32_16x16x32_bf16(a2[t][0], B2[0], zero, 0, 0, 0);
        #pragma unroll
        for (int t = 0; t < 4; ++t)
            acc2[t] = __builtin_amdgcn_mfma_f32_16x16x32_bf16(a2[t][1], B2[1], acc2[t], 0, 0, 0);

        // ---- relu + repack -> B3 ----
        bf16x8 B3[2];
        #pragma unroll
        for (int st = 0; st < 2; ++st) {
            FragU q;
            q.u[0] = pkbf16(fmaxf(acc2[st*2][0],   0.f), fmaxf(acc2[st*2][1],   0.f));
            q.u[1] = pkbf16(fmaxf(acc2[st*2][2],   0.f), fmaxf(acc2[st*2][3],   0.f));
            q.u[2] = pkbf16(fmaxf(acc2[st*2+1][0], 0.f), fmaxf(acc2[st*2+1][1], 0.f));
            q.u[3] = pkbf16(fmaxf(acc2[st*2+1][2], 0.f), fmaxf(acc2[st*2+1][3], 0.f));
            B3[st] = q.v;
        }

        // ---- layer 3 (channel c lives at D row 4c -> lane hi==c, reg 0) ----
        f32x4 acc3 = __builtin_amdgcn_mfma_f32_16x16x32_bf16(a3[0], B3[0], zero, 0, 0, 0);
        acc3 = __builtin_amdgcn_mfma_f32_16x16x32_bf16(a3[1], B3[1], acc3, 0, 0, 0);

        // ---- sigmoid + contiguous store: 48 lanes, 192B/wave ----
        float o = __fdividef(1.0f, 1.0f + __expf(-acc3[0]));
        if (hi < 3) {
            out[(size_t)g * 48 + (unsigned)s * 3 + (unsigned)hi] = o;
        }
        g = gn;
    }
}

extern "C" void kernel_launch(void* const* d_in, const int* in_sizes, int n_in,
                              void* d_out, int out_size, void* d_ws, size_t ws_size,
                              hipStream_t stream) {
    const float* features = (const float*)d_in[0];
    const float* dirs     = (const float*)d_in[1];
    const float* normals  = (const float*)d_in[2];
    const float* W1       = (const float*)d_in[3];
    const float* W2       = (const float*)d_in[4];
    const float* W3       = (const float*)d_in[5];
    float* out = (float*)d_out;

    radiance_mfma4_kernel<<<NBLOCK, 256, 0, stream>>>(
        features, dirs, normals, W1, W2, W3, out);
}